// Round 1
// baseline (519.794 us; speedup 1.0000x reference)
//
#include <hip/hip_runtime.h>
#include <math.h>

// Problem constants
constexpr int KDIM = 784;        // feature dim
constexpr int NA   = 30;         // number of angles = 2*(4*4-1)
constexpr int KC   = 32;         // k-chunk size (full cache line per row)
constexpr int ROWS = 64;         // rows per block (= wavefront)
constexpr int LSTR = 36;         // LDS row stride in floats (padded, 16B-aligned, conflict-optimal)
constexpr int NCHUNK_FULL = 24;  // 24*32 = 768
constexpr int KTAIL = 16;        // 784 - 768

__global__ __launch_bounds__(64, 1)
void fused_rnn_circuit(const float* __restrict__ X,
                       const float* __restrict__ W,
                       const float* __restrict__ Bv,
                       float* __restrict__ out)
{
    const int t = threadIdx.x;
    const long long row0 = (long long)blockIdx.x * ROWS;
    __shared__ float xs[2][ROWS * LSTR];

    float acc[NA];
#pragma unroll
    for (int a = 0; a < NA; ++a) acc[a] = 0.f;

    const float* xbase = X + row0 * KDIM;

    float4 st[8];

    // ---- prologue: load + stage chunk 0 into buffer 0 ----
#pragma unroll
    for (int i = 0; i < 8; ++i) {
        int r = i * 8 + (t >> 3);
        st[i] = *reinterpret_cast<const float4*>(xbase + (long long)r * KDIM + ((t & 7) << 2));
    }
#pragma unroll
    for (int i = 0; i < 8; ++i) {
        int r = i * 8 + (t >> 3);
        *reinterpret_cast<float4*>(&xs[0][r * LSTR + ((t & 7) << 2)]) = st[i];
    }
    __syncthreads();

    // ---- main K loop: 24 full chunks, double buffered ----
    for (int c = 0; c < NCHUNK_FULL; ++c) {
        const int buf = c & 1;
        const int k0  = c * KC;
        const bool havenext = (c + 1 < NCHUNK_FULL);

        // prefetch next chunk into registers (latency hides under FMA phase)
        if (havenext) {
            const int kn = k0 + KC;
#pragma unroll
            for (int i = 0; i < 8; ++i) {
                int r = i * 8 + (t >> 3);
                st[i] = *reinterpret_cast<const float4*>(xbase + (long long)r * KDIM + kn + ((t & 7) << 2));
            }
        }

        // read this thread's row chunk from LDS
        float xv[KC];
#pragma unroll
        for (int q = 0; q < 8; ++q) {
            float4 v = *reinterpret_cast<const float4*>(&xs[buf][t * LSTR + (q << 2)]);
            xv[q * 4 + 0] = v.x; xv[q * 4 + 1] = v.y;
            xv[q * 4 + 2] = v.z; xv[q * 4 + 3] = v.w;
        }

        // 30 x 32 FMAs; W reads are wave-uniform -> scalar loads
#pragma unroll
        for (int a = 0; a < NA; ++a) {
            const float* wr = W + a * KDIM + k0;
            float s0 = acc[a];
#pragma unroll
            for (int j = 0; j < KC; ++j) s0 = fmaf(xv[j], wr[j], s0);
            acc[a] = s0;
        }

        // stage prefetched chunk into the other buffer
        if (havenext) {
#pragma unroll
            for (int i = 0; i < 8; ++i) {
                int r = i * 8 + (t >> 3);
                *reinterpret_cast<float4*>(&xs[buf ^ 1][r * LSTR + ((t & 7) << 2)]) = st[i];
            }
        }
        __syncthreads();
    }

    // ---- tail chunk: k0 = 768, 16 columns ----
    {
#pragma unroll
        for (int i = 0; i < 4; ++i) {
            int r = i * 16 + (t >> 2);
            float4 v = *reinterpret_cast<const float4*>(xbase + (long long)r * KDIM + 768 + ((t & 3) << 2));
            *reinterpret_cast<float4*>(&xs[0][r * LSTR + ((t & 3) << 2)]) = v;
        }
        __syncthreads();

        float xv[KTAIL];
#pragma unroll
        for (int q = 0; q < 4; ++q) {
            float4 v = *reinterpret_cast<const float4*>(&xs[0][t * LSTR + (q << 2)]);
            xv[q * 4 + 0] = v.x; xv[q * 4 + 1] = v.y;
            xv[q * 4 + 2] = v.z; xv[q * 4 + 3] = v.w;
        }
#pragma unroll
        for (int a = 0; a < NA; ++a) {
            const float* wr = W + a * KDIM + 768;
            float s0 = acc[a];
#pragma unroll
            for (int j = 0; j < KTAIL; ++j) s0 = fmaf(xv[j], wr[j], s0);
            acc[a] = s0;
        }
    }

    // ---- angles = acc + bias ----
    float ang[NA];
#pragma unroll
    for (int a = 0; a < NA; ++a) ang[a] = acc[a] + Bv[a];

    // ---- 4-qubit statevector simulation in registers ----
    // index = b0*8 + b1*4 + b2*2 + b3 ; wire w <-> bit position (3-w)
    float sr[16], si[16];
#pragma unroll
    for (int q = 0; q < 16; ++q) { sr[q] = 0.f; si[q] = 0.f; }
    sr[0] = 1.f;

    auto u3 = [&](int w, float th, float ph, float la) {
        float ch, sh;  __sincosf(0.5f * th, &sh, &ch);
        float elr, eli; __sincosf(la, &eli, &elr);
        float epr, epi; __sincosf(ph, &epi, &epr);
        float eer = epr * elr - epi * eli;   // ep*el
        float eei = epr * eli + epi * elr;
        const int m = 1 << (3 - w);
#pragma unroll
        for (int idx = 0; idx < 16; ++idx) {
            if (idx & m) continue;
            int i1 = idx + m;
            float o0r = sr[idx], o0i = si[idx], o1r = sr[i1], o1i = si[i1];
            // n0 = c*o0 - s*(el*o1)
            float e1r = elr * o1r - eli * o1i;
            float e1i = elr * o1i + eli * o1r;
            sr[idx] = ch * o0r - sh * e1r;
            si[idx] = ch * o0i - sh * e1i;
            // n1 = s*(ep*o0) + c*(ep*el*o1)
            float p0r = epr * o0r - epi * o0i;
            float p0i = epr * o0i + epi * o0r;
            float q1r = eer * o1r - eei * o1i;
            float q1i = eer * o1i + eei * o1r;
            sr[i1] = sh * p0r + ch * q1r;
            si[i1] = sh * p0i + ch * q1i;
        }
    };

#pragma unroll
    for (int lay = 0; lay < 2; ++lay) {
        const int base = lay * 15;
#pragma unroll
        for (int i = 0; i < 3; ++i) {
            // RXX(theta) on wires (i, i+1): mixes (00,11) and (01,10) with c, -i*s
            {
                float th = ang[base + i * 4];
                float ch, sh; __sincosf(0.5f * th, &sh, &ch);
                const int m1 = 1 << (3 - i);
                const int m2 = 1 << (2 - i);
#pragma unroll
                for (int b0 = 0; b0 < 16; ++b0) {
                    if (b0 & (m1 | m2)) continue;
                    int i00 = b0, i01 = b0 + m2, i10 = b0 + m1, i11 = b0 + m1 + m2;
                    float o00r = sr[i00], o00i = si[i00], o11r = sr[i11], o11i = si[i11];
                    sr[i00] = ch * o00r + sh * o11i;
                    si[i00] = ch * o00i - sh * o11r;
                    sr[i11] = ch * o11r + sh * o00i;
                    si[i11] = ch * o11i - sh * o00r;
                    float o01r = sr[i01], o01i = si[i01], o10r = sr[i10], o10i = si[i10];
                    sr[i01] = ch * o01r + sh * o10i;
                    si[i01] = ch * o01i - sh * o10r;
                    sr[i10] = ch * o10r + sh * o01i;
                    si[i10] = ch * o10i - sh * o01r;
                }
            }
            // U3 on wire i
            u3(i, ang[base + i * 4 + 1], ang[base + i * 4 + 2], ang[base + i * 4 + 3]);
        }
        // final U3 on wire 3
        u3(3, ang[base + 12], ang[base + 13], ang[base + 14]);
    }

    // ---- store: out[row][j][0]=re, [1]=im  -> 128B per row ----
    float* orow = out + (row0 + t) * 32;
#pragma unroll
    for (int q = 0; q < 8; ++q) {
        float4 v = make_float4(sr[2 * q], si[2 * q], sr[2 * q + 1], si[2 * q + 1]);
        *reinterpret_cast<float4*>(orow + q * 4) = v;
    }
}

extern "C" void kernel_launch(void* const* d_in, const int* in_sizes, int n_in,
                              void* d_out, int out_size, void* d_ws, size_t ws_size,
                              hipStream_t stream) {
    const float* X  = (const float*)d_in[0];
    const float* W  = (const float*)d_in[1];
    const float* Bv = (const float*)d_in[2];
    float* out = (float*)d_out;

    const int Bn = in_sizes[0] / KDIM;   // 65536
    dim3 grid(Bn / ROWS);                // 1024 blocks x 64 threads
    fused_rnn_circuit<<<grid, 64, 0, stream>>>(X, W, Bv, out);
}

// Round 2
// 378.924 us; speedup vs baseline: 1.3718x; 1.3718x over previous
//
#include <hip/hip_runtime.h>
#include <math.h>

// Problem constants
constexpr int KDIM  = 784;   // feature dim
constexpr int NA    = 30;    // number of angles
constexpr int KC    = 32;    // k-chunk columns
constexpr int ROWS  = 64;    // rows per block
constexpr int NW    = 8;     // waves per block
constexpr int NT    = NW * 64;   // 512 threads
constexpr int NCH   = 24;    // full chunks: 24*32 = 768
constexpr int KTAIL = 16;    // 784 - 768

__global__ __launch_bounds__(NT, 8)
void fused_rnn_circuit(const float* __restrict__ X,
                       const float* __restrict__ W,
                       const float* __restrict__ Bv,
                       float* __restrict__ out)
{
    const int t    = threadIdx.x;
    const int lane = t & 63;
    const int w    = t >> 6;                 // wave id 0..7
    const long long row0 = (long long)blockIdx.x * ROWS;

    // chunk tile: 64 rows x 32 floats, linear (global_load_lds needs linear dest);
    // bank conflicts avoided by XOR-swizzling the SOURCE column and the READ offset.
    __shared__ float xs[2][ROWS * KC];       // 2 x 8 KB
    __shared__ float ang[ROWS][33];          // padded stride 33 -> conflict-free gather

    // ---- staging geometry: slot s = w*64 + lane (16B each) covers the 8KB chunk ----
    const int srow = w * 8 + (lane >> 3);            // row this lane stages
    const int sq   = (lane & 7) ^ (srow & 7);        // swizzled source column-block
    const float* gsrc = X + (row0 + srow) * (long long)KDIM + sq * 4;

    auto stage = [&](int c, int buf) {
        const float* gp = gsrc + c * KC;
        float* lp = &xs[buf][w * 256];               // wave-uniform base; HW adds lane*16
        __builtin_amdgcn_global_load_lds(
            (const __attribute__((address_space(1))) void*)gp,
            (__attribute__((address_space(3))) void*)lp, 16, 0, 0);
    };

    // ---- per-thread compute role: row r = lane, angles a0..a0+3 (clamped) ----
    const int r  = lane;
    const int rx = r & 7;
    const int a0 = w * 4;
    int arj[4];
#pragma unroll
    for (int j = 0; j < 4; ++j) { int a = a0 + j; arj[j] = (a < NA) ? a : (NA - 1); }

    float acc[4] = {0.f, 0.f, 0.f, 0.f};

    // prologue: stage chunk 0
    stage(0, 0);
    __syncthreads();

    for (int c = 0; c < NCH; ++c) {
        const int buf = c & 1;
        if (c + 1 < NCH) stage(c + 1, buf ^ 1);

        float xv[KC];
#pragma unroll
        for (int q = 0; q < 8; ++q) {
            float4 v = *reinterpret_cast<const float4*>(&xs[buf][r * KC + ((q ^ rx) << 2)]);
            xv[4 * q + 0] = v.x; xv[4 * q + 1] = v.y;
            xv[4 * q + 2] = v.z; xv[4 * q + 3] = v.w;
        }

#pragma unroll
        for (int j = 0; j < 4; ++j) {
            const float* wr = W + (long long)arj[j] * KDIM + c * KC;   // wave-uniform -> s_load
            float s = acc[j];
#pragma unroll
            for (int k = 0; k < KC; ++k) s = fmaf(xv[k], wr[k], s);
            acc[j] = s;
        }
        __syncthreads();   // drains the chunk c+1 loads; xs[buf^1] ready
    }

    // ---- tail: columns 768..783, direct global (L1/L2-absorbed, 4KB/block) ----
    {
        const float* xt = X + (row0 + r) * (long long)KDIM + NCH * KC;
        float xv[KTAIL];
#pragma unroll
        for (int q = 0; q < 4; ++q) {
            float4 v = *reinterpret_cast<const float4*>(xt + 4 * q);
            xv[4 * q + 0] = v.x; xv[4 * q + 1] = v.y;
            xv[4 * q + 2] = v.z; xv[4 * q + 3] = v.w;
        }
#pragma unroll
        for (int j = 0; j < 4; ++j) {
            const float* wr = W + (long long)arj[j] * KDIM + NCH * KC;
            float s = acc[j];
#pragma unroll
            for (int k = 0; k < KTAIL; ++k) s = fmaf(xv[k], wr[k], s);
            acc[j] = s;
        }
    }

    // ---- gather angles (+bias) into LDS ----
#pragma unroll
    for (int j = 0; j < 4; ++j) {
        int a = a0 + j;
        if (a < NA) ang[r][a] = acc[j] + Bv[a];
    }
    __syncthreads();

    // ---- circuit: wave 0 only, one thread per row ----
    if (t < 64) {
        const float* ap = ang[t];

        float sr[16], si[16];
#pragma unroll
        for (int q = 0; q < 16; ++q) { sr[q] = 0.f; si[q] = 0.f; }
        sr[0] = 1.f;

        auto u3 = [&](int wq, float th, float ph, float la) {
            float ch, sh;  __sincosf(0.5f * th, &sh, &ch);
            float elr, eli; __sincosf(la, &eli, &elr);
            float epr, epi; __sincosf(ph, &epi, &epr);
            float eer = epr * elr - epi * eli;   // ep*el
            float eei = epr * eli + epi * elr;
            const int m = 1 << (3 - wq);
#pragma unroll
            for (int idx = 0; idx < 16; ++idx) {
                if (idx & m) continue;
                int i1 = idx + m;
                float o0r = sr[idx], o0i = si[idx], o1r = sr[i1], o1i = si[i1];
                float e1r = elr * o1r - eli * o1i;
                float e1i = elr * o1i + eli * o1r;
                sr[idx] = ch * o0r - sh * e1r;
                si[idx] = ch * o0i - sh * e1i;
                float p0r = epr * o0r - epi * o0i;
                float p0i = epr * o0i + epi * o0r;
                float q1r = eer * o1r - eei * o1i;
                float q1i = eer * o1i + eei * o1r;
                sr[i1] = sh * p0r + ch * q1r;
                si[i1] = sh * p0i + ch * q1i;
            }
        };

#pragma unroll
        for (int lay = 0; lay < 2; ++lay) {
            const int base = lay * 15;
#pragma unroll
            for (int i = 0; i < 3; ++i) {
                {
                    float th = ap[base + i * 4];
                    float ch, sh; __sincosf(0.5f * th, &sh, &ch);
                    const int m1 = 1 << (3 - i);
                    const int m2 = 1 << (2 - i);
#pragma unroll
                    for (int b0 = 0; b0 < 16; ++b0) {
                        if (b0 & (m1 | m2)) continue;
                        int i00 = b0, i01 = b0 + m2, i10 = b0 + m1, i11 = b0 + m1 + m2;
                        float o00r = sr[i00], o00i = si[i00], o11r = sr[i11], o11i = si[i11];
                        sr[i00] = ch * o00r + sh * o11i;
                        si[i00] = ch * o00i - sh * o11r;
                        sr[i11] = ch * o11r + sh * o00i;
                        si[i11] = ch * o11i - sh * o00r;
                        float o01r = sr[i01], o01i = si[i01], o10r = sr[i10], o10i = si[i10];
                        sr[i01] = ch * o01r + sh * o10i;
                        si[i01] = ch * o01i - sh * o10r;
                        sr[i10] = ch * o10r + sh * o01i;
                        si[i10] = ch * o10i - sh * o01r;
                    }
                }
                u3(i, ap[base + i * 4 + 1], ap[base + i * 4 + 2], ap[base + i * 4 + 3]);
            }
            u3(3, ap[base + 12], ap[base + 13], ap[base + 14]);
        }

        float* orow = out + (row0 + t) * 32;
#pragma unroll
        for (int q = 0; q < 8; ++q) {
            float4 v = make_float4(sr[2 * q], si[2 * q], sr[2 * q + 1], si[2 * q + 1]);
            *reinterpret_cast<float4*>(orow + q * 4) = v;
        }
    }
}

extern "C" void kernel_launch(void* const* d_in, const int* in_sizes, int n_in,
                              void* d_out, int out_size, void* d_ws, size_t ws_size,
                              hipStream_t stream) {
    const float* X  = (const float*)d_in[0];
    const float* W  = (const float*)d_in[1];
    const float* Bv = (const float*)d_in[2];
    float* out = (float*)d_out;

    const int Bn = in_sizes[0] / KDIM;   // 65536
    dim3 grid(Bn / ROWS);                // 1024 blocks x 512 threads
    fused_rnn_circuit<<<grid, NT, 0, stream>>>(X, W, Bv, out);
}

// Round 3
// 103.087 us; speedup vs baseline: 5.0423x; 3.6758x over previous
//
#include <hip/hip_runtime.h>
#include <math.h>

// Problem constants
constexpr int KDIM  = 784;   // feature dim
constexpr int NA    = 30;    // number of angles
constexpr int KC    = 32;    // k-chunk columns
constexpr int ROWS  = 64;    // rows per block
constexpr int NW    = 4;     // waves per block
constexpr int NT    = NW * 64;   // 256 threads
constexpr int APT   = 8;     // angles per thread
constexpr int NCH   = 24;    // full chunks: 24*32 = 768
constexpr int KTAIL = 16;    // 784 - 768

__global__ __launch_bounds__(NT, 4)
void fused_rnn_circuit(const float* __restrict__ X,
                       const float* __restrict__ W,
                       const float* __restrict__ Bv,
                       float* __restrict__ out)
{
    const int t    = threadIdx.x;
    const int lane = t & 63;
    const int w    = t >> 6;                 // wave id 0..3
    const long long row0 = (long long)blockIdx.x * ROWS;

    // chunk tile: 64 rows x 32 floats (8 KB), linear slot order = staging order.
    // slot s holds (row = s>>3, colblk = (s&7) ^ (row&7))  [XOR source swizzle]
    __shared__ float xs[2][ROWS * KC];       // 2 x 8 KB
    __shared__ float ang[ROWS][33];          // padded stride 33 -> conflict-free

    // ---- staging: 512 slots/chunk, 256 threads -> 2 global_load_lds each ----
    // call k covers slots k*256 + t : row = k*32 + (t>>3), colblk = (t&7)^((t>>3)&7)
    const int srow = t >> 3;
    const int sq   = (t & 7) ^ (srow & 7);
    const float* gsrc0 = X + (row0 + srow)      * (long long)KDIM + sq * 4;
    const float* gsrc1 = X + (row0 + 32 + srow) * (long long)KDIM + sq * 4;

    auto stage = [&](int c, int buf) {
        const float* g0 = gsrc0 + c * KC;
        const float* g1 = gsrc1 + c * KC;
        __builtin_amdgcn_global_load_lds(
            (const __attribute__((address_space(1))) void*)g0,
            (__attribute__((address_space(3))) void*)&xs[buf][w * 256], 16, 0, 0);
        __builtin_amdgcn_global_load_lds(
            (const __attribute__((address_space(1))) void*)g1,
            (__attribute__((address_space(3))) void*)&xs[buf][1024 + w * 256], 16, 0, 0);
    };

    // ---- compute roles: row r = lane; angles w*8 .. w*8+7 (clamped) ----
    const int r  = lane;
    const int rx = r & 7;
    int arj[APT];
#pragma unroll
    for (int j = 0; j < APT; ++j) {
        int a = w * APT + j;
        arj[j] = __builtin_amdgcn_readfirstlane(a < NA ? a : NA - 1);  // force SGPR
    }

    float acc[APT];
#pragma unroll
    for (int j = 0; j < APT; ++j) acc[j] = 0.f;

    // prologue
    stage(0, 0);
    __syncthreads();

    for (int c = 0; c < NCH; ++c) {
        const int buf = c & 1;
        if (c + 1 < NCH) stage(c + 1, buf ^ 1);

        float xv[KC];
#pragma unroll
        for (int q = 0; q < 8; ++q) {
            float4 v = *reinterpret_cast<const float4*>(&xs[buf][r * KC + ((q ^ rx) << 2)]);
            xv[4 * q + 0] = v.x; xv[4 * q + 1] = v.y;
            xv[4 * q + 2] = v.z; xv[4 * q + 3] = v.w;
        }

#pragma unroll
        for (int j = 0; j < APT; ++j) {
            const float* wr = W + (long long)arj[j] * KDIM + c * KC;   // SGPR base -> s_load
            float s = acc[j];
#pragma unroll
            for (int k = 0; k < KC; ++k) s = fmaf(xv[k], wr[k], s);
            acc[j] = s;
        }
        __syncthreads();   // drains chunk c+1 loads; protects buf reuse
    }

    // ---- tail: columns 768..783, direct global (L1-served, 64B/row) ----
    {
        const float* xt = X + (row0 + r) * (long long)KDIM + NCH * KC;
        float xv[KTAIL];
#pragma unroll
        for (int q = 0; q < 4; ++q) {
            float4 v = *reinterpret_cast<const float4*>(xt + 4 * q);
            xv[4 * q + 0] = v.x; xv[4 * q + 1] = v.y;
            xv[4 * q + 2] = v.z; xv[4 * q + 3] = v.w;
        }
#pragma unroll
        for (int j = 0; j < APT; ++j) {
            const float* wr = W + (long long)arj[j] * KDIM + NCH * KC;
            float s = acc[j];
#pragma unroll
            for (int k = 0; k < KTAIL; ++k) s = fmaf(xv[k], wr[k], s);
            acc[j] = s;
        }
    }

    // ---- gather angles (+bias) into LDS ----
#pragma unroll
    for (int j = 0; j < APT; ++j) {
        int a = w * APT + j;
        if (a < NA) ang[r][a] = acc[j] + Bv[a];
    }
    __syncthreads();

    // ---- circuit: wave 0 only, one thread per row ----
    if (t < 64) {
        const float* ap = ang[t];

        float sr[16], si[16];
#pragma unroll
        for (int q = 0; q < 16; ++q) { sr[q] = 0.f; si[q] = 0.f; }
        sr[0] = 1.f;

        auto u3 = [&](int wq, float th, float ph, float la) {
            float ch, sh;  __sincosf(0.5f * th, &sh, &ch);
            float elr, eli; __sincosf(la, &eli, &elr);
            float epr, epi; __sincosf(ph, &epi, &epr);
            float eer = epr * elr - epi * eli;   // ep*el
            float eei = epr * eli + epi * elr;
            const int m = 1 << (3 - wq);
#pragma unroll
            for (int idx = 0; idx < 16; ++idx) {
                if (idx & m) continue;
                int i1 = idx + m;
                float o0r = sr[idx], o0i = si[idx], o1r = sr[i1], o1i = si[i1];
                float e1r = elr * o1r - eli * o1i;
                float e1i = elr * o1i + eli * o1r;
                sr[idx] = ch * o0r - sh * e1r;
                si[idx] = ch * o0i - sh * e1i;
                float p0r = epr * o0r - epi * o0i;
                float p0i = epr * o0i + epi * o0r;
                float q1r = eer * o1r - eei * o1i;
                float q1i = eer * o1i + eei * o1r;
                sr[i1] = sh * p0r + ch * q1r;
                si[i1] = sh * p0i + ch * q1i;
            }
        };

#pragma unroll
        for (int lay = 0; lay < 2; ++lay) {
            const int base = lay * 15;
#pragma unroll
            for (int i = 0; i < 3; ++i) {
                {
                    float th = ap[base + i * 4];
                    float ch, sh; __sincosf(0.5f * th, &sh, &ch);
                    const int m1 = 1 << (3 - i);
                    const int m2 = 1 << (2 - i);
#pragma unroll
                    for (int b0 = 0; b0 < 16; ++b0) {
                        if (b0 & (m1 | m2)) continue;
                        int i00 = b0, i01 = b0 + m2, i10 = b0 + m1, i11 = b0 + m1 + m2;
                        float o00r = sr[i00], o00i = si[i00], o11r = sr[i11], o11i = si[i11];
                        sr[i00] = ch * o00r + sh * o11i;
                        si[i00] = ch * o00i - sh * o11r;
                        sr[i11] = ch * o11r + sh * o00i;
                        si[i11] = ch * o11i - sh * o00r;
                        float o01r = sr[i01], o01i = si[i01], o10r = sr[i10], o10i = si[i10];
                        sr[i01] = ch * o01r + sh * o10i;
                        si[i01] = ch * o01i - sh * o10r;
                        sr[i10] = ch * o10r + sh * o01i;
                        si[i10] = ch * o10i - sh * o01r;
                    }
                }
                u3(i, ap[base + i * 4 + 1], ap[base + i * 4 + 2], ap[base + i * 4 + 3]);
            }
            u3(3, ap[base + 12], ap[base + 13], ap[base + 14]);
        }

        float* orow = out + (row0 + t) * 32;
#pragma unroll
        for (int q = 0; q < 8; ++q) {
            float4 v = make_float4(sr[2 * q], si[2 * q], sr[2 * q + 1], si[2 * q + 1]);
            *reinterpret_cast<float4*>(orow + q * 4) = v;
        }
    }
}

extern "C" void kernel_launch(void* const* d_in, const int* in_sizes, int n_in,
                              void* d_out, int out_size, void* d_ws, size_t ws_size,
                              hipStream_t stream) {
    const float* X  = (const float*)d_in[0];
    const float* W  = (const float*)d_in[1];
    const float* Bv = (const float*)d_in[2];
    float* out = (float*)d_out;

    const int Bn = in_sizes[0] / KDIM;   // 65536
    dim3 grid(Bn / ROWS);                // 1024 blocks x 256 threads
    fused_rnn_circuit<<<grid, NT, 0, stream>>>(X, W, Bv, out);
}